// Round 5
// baseline (11152.914 us; speedup 1.0000x reference)
//
#include <hip/hip_runtime.h>
#include <math.h>

typedef unsigned long long u64;
typedef unsigned int u32;

#define B_     4
#define CIN    1024
#define COUT   512
#define H_     64
#define W_     96
#define HW     6144
#define NANCH  55296
#define TOPN   6000
#define POST   300
#define CAP    6144
#define SCAP   8192

// workspace offsets (bytes, 256-aligned); total ~17.8 MB
#define OFF_RPN    0ull
#define OFF_SCORES 12582912ull
#define OFF_PROP   13467648ull
#define OFF_SKEYS  17006592ull
#define OFF_SIDS   17137664ull
#define OFF_KTH    17268736ull
#define OFF_CNT    17268992ull
#define OFF_TID    17269248ull
#define OFF_TB     17367552ull
#define OFF_KEEP   17760768ull

__constant__ float BAf[9][4] = {
  {-84.f,-40.f,99.f,55.f},
  {-176.f,-88.f,191.f,103.f},
  {-360.f,-184.f,375.f,199.f},
  {-56.f,-56.f,71.f,71.f},
  {-120.f,-120.f,135.f,135.f},
  {-248.f,-248.f,263.f,263.f},
  {-36.f,-80.f,51.f,95.f},
  {-80.f,-168.f,95.f,183.f},
  {-168.f,-344.f,183.f,359.f}
};

// ---------------- 3x3 conv + bias + relu, fp32 accumulate, one batch ----------------
// K-order (ci, kh, kw) = NCHW im2col; bias added after full accumulation (XLA style).
__global__ __launch_bounds__(256) void conv3_k(int b, const float* __restrict__ x,
                                               const float* __restrict__ w,
                                               const float* __restrict__ bias,
                                               float* __restrict__ y) {
  __shared__ float patch[8][10][34];
  __shared__ float wl[8][32][9];
  const int tid = threadIdx.x;
  const int cog = blockIdx.x & 15, w3 = blockIdx.x >> 4;
  const int h0 = blockIdx.y * 8;
  const int co0 = cog * 32, w0 = w3 * 32;
  const int tm = tid & 31, tn = tid >> 5;

  float acc[8][4];
#pragma unroll
  for (int i = 0; i < 8; ++i)
#pragma unroll
    for (int cc = 0; cc < 4; ++cc)
      acc[i][cc] = 0.f;

  for (int c0 = 0; c0 < CIN; c0 += 8) {
    __syncthreads();
    for (int e = tid; e < 2720; e += 256) {
      int ci = e / 340, rem = e - ci * 340;
      int r = rem / 34, c = rem - r * 34;
      int hh = h0 - 1 + r, ww = w0 - 1 + c;
      float v = 0.f;
      if ((unsigned)hh < 64u && (unsigned)ww < 96u)
        v = x[(((size_t)b * CIN + c0 + ci) * H_ + hh) * W_ + ww];
      patch[ci][r][c] = v;
    }
    for (int e = tid; e < 2304; e += 256) {
      int ci = e / 288, rem = e - ci * 288;
      int co = rem / 9, k = rem - co * 9;
      wl[ci][co][k] = w[(((size_t)(co0 + co)) * CIN + c0 + ci) * 9 + k];
    }
    __syncthreads();
    for (int ci = 0; ci < 8; ++ci) {
#pragma unroll
      for (int kh = 0; kh < 3; ++kh) {
        float row[10];
#pragma unroll
        for (int kw = 0; kw < 3; ++kw) {
#pragma unroll
          for (int i = 0; i < 8; ++i) row[i] = patch[ci][i + kh][tm + kw];
#pragma unroll
          for (int cc = 0; cc < 4; ++cc) {
            float wv = wl[ci][tn * 4 + cc][kh * 3 + kw];
#pragma unroll
            for (int i = 0; i < 8; ++i)
              acc[i][cc] = fmaf(row[i], wv, acc[i][cc]);
          }
        }
      }
    }
  }

#pragma unroll
  for (int cc = 0; cc < 4; ++cc) {
    float bv = bias[co0 + tn * 4 + cc];
#pragma unroll
    for (int i = 0; i < 8; ++i) {
      float v = acc[i][cc] + bv;
      v = v > 0.f ? v : 0.f;
      y[(((size_t)(co0 + tn * 4 + cc)) * H_ + (h0 + i)) * W_ + (w0 + tm)] = v;
    }
  }
}

// ------------- 1x1 heads + softmax + decode + clip (fp32), one batch -------------
__global__ __launch_bounds__(256) void head_k(int b, const float* __restrict__ rpn,
    const float* __restrict__ wc, const float* __restrict__ bc,
    const float* __restrict__ wb, const float* __restrict__ bb,
    const float* __restrict__ iminfo,
    float* __restrict__ scores, float* __restrict__ prop) {
  __shared__ float wl[54][64];
  const int tid = threadIdx.x;
  const int s = blockIdx.x * 256 + tid;   // < 6144, uniform

  float acc[54];
  for (int o = 0; o < 54; ++o) acc[o] = 0.f;

  for (int c0 = 0; c0 < COUT; c0 += 64) {
    __syncthreads();
    for (int e = tid; e < 54 * 64; e += 256) {
      int o = e >> 6, c = e & 63;
      wl[o][c] = (o < 18 ? wc[o * COUT + c0 + c] : wb[(o - 18) * COUT + c0 + c]);
    }
    __syncthreads();
    for (int c = 0; c < 64; ++c) {
      float xv = rpn[((size_t)(c0 + c)) * HW + s];
      for (int o = 0; o < 54; ++o) acc[o] = fmaf(wl[o][c], xv, acc[o]);
    }
  }

  const float imh = iminfo[b * 3 + 0];
  const float imw = iminfo[b * 3 + 1];
  const int hh = s / W_, ww = s - hh * W_;

#pragma unroll
  for (int a = 0; a < 9; ++a) {
    float z0 = acc[a] + bc[a];
    float z1 = acc[9 + a] + bc[9 + a];
    float m = fmaxf(z0, z1);
    float e0 = expf(z0 - m), e1 = expf(z1 - m);
    float sc = e1 / (e0 + e1);

    float d0 = acc[18 + 4 * a + 0] + bb[4 * a + 0];
    float d1 = acc[18 + 4 * a + 1] + bb[4 * a + 1];
    float d2 = acc[18 + 4 * a + 2] + bb[4 * a + 2];
    float d3 = acc[18 + 4 * a + 3] + bb[4 * a + 3];

    float ax1 = BAf[a][0] + 16.f * ww, ay1 = BAf[a][1] + 16.f * hh;
    float ax2 = BAf[a][2] + 16.f * ww, ay2 = BAf[a][3] + 16.f * hh;
    float wa = ax2 - ax1 + 1.f, ha = ay2 - ay1 + 1.f;
    float cxa = ax1 + 0.5f * wa, cya = ay1 + 0.5f * ha;
    float cx = d0 * wa + cxa, cy = d1 * ha + cya;
    float pw = expf(d2) * wa, ph = expf(d3) * ha;
    float px1 = cx - 0.5f * pw, py1 = cy - 0.5f * ph;
    float px2 = cx + 0.5f * pw, py2 = cy + 0.5f * ph;
    px1 = fminf(fmaxf(px1, 0.f), imw - 1.f);
    px2 = fminf(fmaxf(px2, 0.f), imw - 1.f);
    py1 = fminf(fmaxf(py1, 0.f), imh - 1.f);
    py2 = fminf(fmaxf(py2, 0.f), imh - 1.f);

    size_t ai = (size_t)b * NANCH + (size_t)s * 9 + a;
    scores[ai] = sc;
    prop[ai * 4 + 0] = px1; prop[ai * 4 + 1] = py1;
    prop[ai * 4 + 2] = px2; prop[ai * 4 + 3] = py2;
  }
}

// ---------------- exact top-6000 selection on f32-bit keys ----------------
// scores >= 0 -> u32 bits are order-isomorphic
__global__ __launch_bounds__(1024) void select_k(const float* __restrict__ scores,
                                                 u32* __restrict__ kth) {
  __shared__ u32 hist[256];
  __shared__ u32 sh_pref;
  __shared__ u32 sh_r;
  const int b = blockIdx.x, tid = threadIdx.x;
  const float* sb = scores + (size_t)b * NANCH;
  if (tid == 0) { sh_pref = 0u; sh_r = TOPN; }
  __syncthreads();
  for (int d = 3; d >= 0; --d) {
    if (tid < 256) hist[tid] = 0;
    __syncthreads();
    u32 pref = sh_pref;
    u32 mask = (d == 3) ? 0u : (0xFFFFFFFFu << ((d + 1) * 8));
    for (int g = tid; g < NANCH; g += 1024) {
      u32 k = __float_as_uint(sb[g]);
      if ((k & mask) == pref)
        atomicAdd(&hist[(k >> (d * 8)) & 0xFFu], 1u);
    }
    __syncthreads();
    if (tid == 0) {
      u32 r = sh_r, cum = 0;
      for (int bin = 255; bin >= 0; --bin) {
        u32 c = hist[bin];
        if (cum + c >= r) { sh_r = r - cum; sh_pref = pref | ((u32)bin << (d * 8)); break; }
        cum += c;
      }
    }
    __syncthreads();
  }
  if (tid == 0) kth[b] = sh_pref;
}

__global__ void init_k(u32* cnt) {
  if (threadIdx.x < B_) cnt[threadIdx.x] = 0;
}

__global__ __launch_bounds__(256) void compact_k(const float* __restrict__ scores,
                                                 const u32* __restrict__ kth,
                                                 u32* __restrict__ skeys, u32* __restrict__ sids,
                                                 u32* __restrict__ cnt) {
  const int b = blockIdx.y;
  const int g = blockIdx.x * 256 + threadIdx.x;
  if (g >= NANCH) return;
  u32 k = __float_as_uint(scores[(size_t)b * NANCH + g]);
  if (k >= kth[b]) {
    u32 slot = atomicAdd(&cnt[b], 1u);
    if (slot < SCAP) { skeys[(size_t)b * SCAP + slot] = k; sids[(size_t)b * SCAP + slot] = (u32)g; }
  }
}

__device__ inline bool prec_(u32 ka, u32 ia, u32 kb, u32 ib) {
  return (ka > kb) || (ka == kb && ia < ib);
}

__global__ __launch_bounds__(1024) void sort8k_k(const u32* __restrict__ skeys,
                                                 const u32* __restrict__ sids,
                                                 const u32* __restrict__ cnt,
                                                 u32* __restrict__ top_ids) {
  __shared__ u32 sk[SCAP];
  __shared__ u32 si[SCAP];
  const int b = blockIdx.x, tid = threadIdx.x;
  u32 cb = cnt[b]; if (cb > SCAP) cb = SCAP;
  for (int e = tid; e < SCAP; e += 1024) {
    u32 k = 0u; u32 id = 0xFFFFFFFFu;
    if (e < (int)cb) { k = skeys[(size_t)b * SCAP + e]; id = sids[(size_t)b * SCAP + e]; }
    sk[e] = k; si[e] = id;
  }
  __syncthreads();
  for (int k = 2; k <= SCAP; k <<= 1) {
    for (int j = k >> 1; j > 0; j >>= 1) {
      for (int t = tid; t < SCAP / 2; t += 1024) {
        int i = ((t & ~(j - 1)) << 1) | (t & (j - 1));
        int p2 = i | j;
        bool gf = ((i & k) == 0);   // final list descending
        u32 k1 = sk[i], k2 = sk[p2];
        u32 i1 = si[i], i2 = si[p2];
        bool sw = gf ? prec_(k2, i2, k1, i1) : prec_(k1, i1, k2, i2);
        if (sw) { sk[i] = k2; si[i] = i2; sk[p2] = k1; si[p2] = i1; }
      }
      __syncthreads();
    }
  }
  for (int e = tid; e < CAP; e += 1024)
    top_ids[(size_t)b * CAP + e] = si[e];
}

__global__ __launch_bounds__(256) void gather_k(const u32* __restrict__ top_ids,
                                                const float* __restrict__ prop,
                                                float* __restrict__ tb) {
  int t = blockIdx.x * 256 + threadIdx.x;
  if (t >= B_ * TOPN) return;
  int b = t / TOPN, r = t - b * TOPN;
  u32 g = top_ids[(size_t)b * CAP + r];
  size_t src = ((size_t)b * NANCH + g) * 4;
  size_t dst = ((size_t)b * CAP + r) * 4;
  tb[dst + 0] = prop[src + 0]; tb[dst + 1] = prop[src + 1];
  tb[dst + 2] = prop[src + 2]; tb[dst + 3] = prop[src + 3];
}

// ---------------- naive fused greedy NMS (f32), one block per batch ----------------
__global__ __launch_bounds__(256) void nmsfused_k(const float* __restrict__ tb,
                                                  int* __restrict__ keep) {
  __shared__ unsigned char valid[TOPN];
  __shared__ int red[256];
  __shared__ float jb[5];
  __shared__ int sj;
  const int b = blockIdx.x, tid = threadIdx.x;

  for (int i = tid; i < TOPN; i += 256) valid[i] = 1;
  __syncthreads();

  for (int it = 0; it < POST; ++it) {
    int loc = 0x7FFFFFFF;
    for (int i = tid; i < TOPN; i += 256) {
      if (valid[i]) { loc = i; break; }
    }
    red[tid] = loc;
    __syncthreads();
    for (int s = 128; s > 0; s >>= 1) {
      if (tid < s) { int o = red[tid + s]; if (o < red[tid]) red[tid] = o; }
      __syncthreads();
    }
    if (tid == 0) {
      int j = red[0];
      sj = j;
      keep[b * POST + it] = (j == 0x7FFFFFFF) ? -1 : j;
      if (j != 0x7FFFFFFF) {
        size_t o = ((size_t)b * CAP + j) * 4;
        jb[0] = tb[o]; jb[1] = tb[o + 1]; jb[2] = tb[o + 2]; jb[3] = tb[o + 3];
        jb[4] = (jb[2] - jb[0] + 1.f) * (jb[3] - jb[1] + 1.f);
      }
    }
    __syncthreads();
    int j = sj;
    if (j != 0x7FFFFFFF) {
      float jx1 = jb[0], jy1 = jb[1], jx2 = jb[2], jy2 = jb[3], jar = jb[4];
      for (int i = tid; i < TOPN; i += 256) {
        if (!valid[i]) continue;
        size_t o = ((size_t)b * CAP + i) * 4;
        float x1 = tb[o], y1 = tb[o + 1], x2 = tb[o + 2], y2 = tb[o + 3];
        float ai = (x2 - x1 + 1.f) * (y2 - y1 + 1.f);
        float xx1 = fmaxf(jx1, x1), yy1 = fmaxf(jy1, y1);
        float xx2 = fminf(jx2, x2), yy2 = fminf(jy2, y2);
        float iw = fmaxf(xx2 - xx1 + 1.f, 0.f), ih = fmaxf(yy2 - yy1 + 1.f, 0.f);
        float inter = iw * ih;
        float iou = inter / (jar + ai - inter);
        if (iou > 0.7f) valid[i] = 0;
      }
    }
    __syncthreads();
  }
}

__global__ __launch_bounds__(256) void write_k(const int* __restrict__ keep,
                                               const float* __restrict__ tb,
                                               float* __restrict__ out) {
  int t = blockIdx.x * 256 + threadIdx.x;
  if (t >= B_ * POST) return;
  int b = t / POST;
  int r = keep[t];
  float* o = out + (size_t)t * 5;
  o[0] = (float)b;
  if (r >= 0) {
    size_t s = ((size_t)b * CAP + r) * 4;
    o[1] = tb[s]; o[2] = tb[s + 1];
    o[3] = tb[s + 2]; o[4] = tb[s + 3];
  } else {
    o[1] = 0.f; o[2] = 0.f; o[3] = 0.f; o[4] = 0.f;
  }
}

extern "C" void kernel_launch(void* const* d_in, const int* in_sizes, int n_in,
                              void* d_out, int out_size, void* d_ws, size_t ws_size,
                              hipStream_t stream) {
  const float* base_feat = (const float*)d_in[0];
  const float* im_info   = (const float*)d_in[1];
  const float* conv_w = (const float*)d_in[4];
  const float* conv_b = (const float*)d_in[5];
  const float* cls_w  = (const float*)d_in[6];
  const float* cls_b  = (const float*)d_in[7];
  const float* bbox_w = (const float*)d_in[8];
  const float* bbox_b = (const float*)d_in[9];

  char* ws = (char*)d_ws;
  float* rpn    = (float*)(ws + OFF_RPN);     // one batch at a time (12.6 MB)
  float* scores = (float*)(ws + OFF_SCORES);
  float* prop   = (float*)(ws + OFF_PROP);
  u32* skeys = (u32*)(ws + OFF_SKEYS);
  u32* sids  = (u32*)(ws + OFF_SIDS);
  u32* kth   = (u32*)(ws + OFF_KTH);
  u32* cnt   = (u32*)(ws + OFF_CNT);
  u32* tids  = (u32*)(ws + OFF_TID);
  float* topbox = (float*)(ws + OFF_TB);
  int* keep  = (int*)(ws + OFF_KEEP);

  for (int b = 0; b < B_; ++b) {
    conv3_k<<<dim3(48, 8), 256, 0, stream>>>(b, base_feat, conv_w, conv_b, rpn);
    head_k<<<24, 256, 0, stream>>>(b, rpn, cls_w, cls_b, bbox_w, bbox_b, im_info, scores, prop);
  }
  select_k<<<B_, 1024, 0, stream>>>(scores, kth);
  init_k<<<1, 64, 0, stream>>>(cnt);
  compact_k<<<dim3(216, B_), 256, 0, stream>>>(scores, kth, skeys, sids, cnt);
  sort8k_k<<<B_, 1024, 0, stream>>>(skeys, sids, cnt, tids);
  gather_k<<<94, 256, 0, stream>>>(tids, prop, topbox);
  nmsfused_k<<<B_, 256, 0, stream>>>(topbox, keep);
  write_k<<<5, 256, 0, stream>>>(keep, topbox, (float*)d_out);
}

// Round 6
// 5246.370 us; speedup vs baseline: 2.1258x; 2.1258x over previous
//
#include <hip/hip_runtime.h>
#include <math.h>

typedef unsigned long long u64;
typedef unsigned int u32;

#define B_     4
#define CIN    1024
#define COUT   512
#define H_     64
#define W_     96
#define HW     6144
#define NANCH  55296
#define TOPN   6000
#define POST   300
#define CAP    6144
#define WORDS  94
#define SCAP   8192

// workspace offsets (bytes, 256-aligned); total ~73.6 MB (ws >= ~135 MB per R1/R2 evidence)
#define OFF_RPN    0ull
#define OFF_SCORES 50331648ull
#define OFF_PROP   51216384ull
#define OFF_SKEYS  54755328ull
#define OFF_SIDS   54886400ull
#define OFF_KTH    55017472ull
#define OFF_CNT    55017728ull
#define OFF_TID    55017984ull
#define OFF_TB     55116288ull
#define OFF_SUPP   55509504ull
#define OFF_KEEP   73557504ull

__constant__ float BAf[9][4] = {
  {-84.f,-40.f,99.f,55.f},
  {-176.f,-88.f,191.f,103.f},
  {-360.f,-184.f,375.f,199.f},
  {-56.f,-56.f,71.f,71.f},
  {-120.f,-120.f,135.f,135.f},
  {-248.f,-248.f,263.f,263.f},
  {-36.f,-80.f,51.f,95.f},
  {-80.f,-168.f,95.f,183.f},
  {-168.f,-344.f,183.f,359.f}
};

// ---------------- 3x3 conv + bias + relu, fp32, all batches (z = batch) ----------------
// NUMERICS FROZEN: per-output FMA chain order (c ascending, kh, kw) must not change —
// it bit-matches the golden reference (round-5 absmax 0.0).
__global__ __launch_bounds__(256) void conv3_k(const float* __restrict__ x,
                                               const float* __restrict__ w,
                                               const float* __restrict__ bias,
                                               float* __restrict__ y) {
  __shared__ float patch[8][10][34];
  __shared__ float wl[8][32][9];
  const int tid = threadIdx.x;
  const int cog = blockIdx.x & 15, w3 = blockIdx.x >> 4;
  const int h0 = blockIdx.y * 8;
  const int b = blockIdx.z;
  const int co0 = cog * 32, w0 = w3 * 32;
  const int tm = tid & 31, tn = tid >> 5;

  float acc[8][4];
#pragma unroll
  for (int i = 0; i < 8; ++i)
#pragma unroll
    for (int cc = 0; cc < 4; ++cc)
      acc[i][cc] = 0.f;

  for (int c0 = 0; c0 < CIN; c0 += 8) {
    __syncthreads();
    for (int e = tid; e < 2720; e += 256) {
      int ci = e / 340, rem = e - ci * 340;
      int r = rem / 34, c = rem - r * 34;
      int hh = h0 - 1 + r, ww = w0 - 1 + c;
      float v = 0.f;
      if ((unsigned)hh < 64u && (unsigned)ww < 96u)
        v = x[(((size_t)b * CIN + c0 + ci) * H_ + hh) * W_ + ww];
      patch[ci][r][c] = v;
    }
    for (int e = tid; e < 2304; e += 256) {
      int ci = e / 288, rem = e - ci * 288;
      int co = rem / 9, k = rem - co * 9;
      wl[ci][co][k] = w[(((size_t)(co0 + co)) * CIN + c0 + ci) * 9 + k];
    }
    __syncthreads();
    for (int ci = 0; ci < 8; ++ci) {
#pragma unroll
      for (int kh = 0; kh < 3; ++kh) {
        float row[10];
#pragma unroll
        for (int kw = 0; kw < 3; ++kw) {
#pragma unroll
          for (int i = 0; i < 8; ++i) row[i] = patch[ci][i + kh][tm + kw];
#pragma unroll
          for (int cc = 0; cc < 4; ++cc) {
            float wv = wl[ci][tn * 4 + cc][kh * 3 + kw];
#pragma unroll
            for (int i = 0; i < 8; ++i)
              acc[i][cc] = fmaf(row[i], wv, acc[i][cc]);
          }
        }
      }
    }
  }

#pragma unroll
  for (int cc = 0; cc < 4; ++cc) {
    float bv = bias[co0 + tn * 4 + cc];
#pragma unroll
    for (int i = 0; i < 8; ++i) {
      float v = acc[i][cc] + bv;
      v = v > 0.f ? v : 0.f;
      y[(((size_t)b * COUT + co0 + tn * 4 + cc) * H_ + (h0 + i)) * W_ + (w0 + tm)] = v;
    }
  }
}

// ------------- 1x1 heads + softmax + decode + clip (fp32), all batches -------------
__global__ __launch_bounds__(256) void head_k(const float* __restrict__ rpn,
    const float* __restrict__ wc, const float* __restrict__ bc,
    const float* __restrict__ wb, const float* __restrict__ bb,
    const float* __restrict__ iminfo,
    float* __restrict__ scores, float* __restrict__ prop) {
  __shared__ float wl[54][64];
  const int tid = threadIdx.x;
  const int s = blockIdx.x * 256 + tid;   // < 6144, uniform
  const int b = blockIdx.y;

  float acc[54];
  for (int o = 0; o < 54; ++o) acc[o] = 0.f;

  for (int c0 = 0; c0 < COUT; c0 += 64) {
    __syncthreads();
    for (int e = tid; e < 54 * 64; e += 256) {
      int o = e >> 6, c = e & 63;
      wl[o][c] = (o < 18 ? wc[o * COUT + c0 + c] : wb[(o - 18) * COUT + c0 + c]);
    }
    __syncthreads();
    for (int c = 0; c < 64; ++c) {
      float xv = rpn[((size_t)b * COUT + c0 + c) * HW + s];
      for (int o = 0; o < 54; ++o) acc[o] = fmaf(wl[o][c], xv, acc[o]);
    }
  }

  const float imh = iminfo[b * 3 + 0];
  const float imw = iminfo[b * 3 + 1];
  const int hh = s / W_, ww = s - hh * W_;

#pragma unroll
  for (int a = 0; a < 9; ++a) {
    float z0 = acc[a] + bc[a];
    float z1 = acc[9 + a] + bc[9 + a];
    float m = fmaxf(z0, z1);
    float e0 = expf(z0 - m), e1 = expf(z1 - m);
    float sc = e1 / (e0 + e1);

    float d0 = acc[18 + 4 * a + 0] + bb[4 * a + 0];
    float d1 = acc[18 + 4 * a + 1] + bb[4 * a + 1];
    float d2 = acc[18 + 4 * a + 2] + bb[4 * a + 2];
    float d3 = acc[18 + 4 * a + 3] + bb[4 * a + 3];

    float ax1 = BAf[a][0] + 16.f * ww, ay1 = BAf[a][1] + 16.f * hh;
    float ax2 = BAf[a][2] + 16.f * ww, ay2 = BAf[a][3] + 16.f * hh;
    float wa = ax2 - ax1 + 1.f, ha = ay2 - ay1 + 1.f;
    float cxa = ax1 + 0.5f * wa, cya = ay1 + 0.5f * ha;
    float cx = d0 * wa + cxa, cy = d1 * ha + cya;
    float pw = expf(d2) * wa, ph = expf(d3) * ha;
    float px1 = cx - 0.5f * pw, py1 = cy - 0.5f * ph;
    float px2 = cx + 0.5f * pw, py2 = cy + 0.5f * ph;
    px1 = fminf(fmaxf(px1, 0.f), imw - 1.f);
    px2 = fminf(fmaxf(px2, 0.f), imw - 1.f);
    py1 = fminf(fmaxf(py1, 0.f), imh - 1.f);
    py2 = fminf(fmaxf(py2, 0.f), imh - 1.f);

    size_t ai = (size_t)b * NANCH + (size_t)s * 9 + a;
    scores[ai] = sc;
    prop[ai * 4 + 0] = px1; prop[ai * 4 + 1] = py1;
    prop[ai * 4 + 2] = px2; prop[ai * 4 + 3] = py2;
  }
}

// ---------------- exact top-6000 selection on f32-bit keys ----------------
__global__ __launch_bounds__(1024) void select_k(const float* __restrict__ scores,
                                                 u32* __restrict__ kth) {
  __shared__ u32 hist[256];
  __shared__ u32 sh_pref;
  __shared__ u32 sh_r;
  const int b = blockIdx.x, tid = threadIdx.x;
  const float* sb = scores + (size_t)b * NANCH;
  if (tid == 0) { sh_pref = 0u; sh_r = TOPN; }
  __syncthreads();
  for (int d = 3; d >= 0; --d) {
    if (tid < 256) hist[tid] = 0;
    __syncthreads();
    u32 pref = sh_pref;
    u32 mask = (d == 3) ? 0u : (0xFFFFFFFFu << ((d + 1) * 8));
    for (int g = tid; g < NANCH; g += 1024) {
      u32 k = __float_as_uint(sb[g]);
      if ((k & mask) == pref)
        atomicAdd(&hist[(k >> (d * 8)) & 0xFFu], 1u);
    }
    __syncthreads();
    if (tid == 0) {
      u32 r = sh_r, cum = 0;
      for (int bin = 255; bin >= 0; --bin) {
        u32 c = hist[bin];
        if (cum + c >= r) { sh_r = r - cum; sh_pref = pref | ((u32)bin << (d * 8)); break; }
        cum += c;
      }
    }
    __syncthreads();
  }
  if (tid == 0) kth[b] = sh_pref;
}

__global__ void init_k(u32* cnt) {
  if (threadIdx.x < B_) cnt[threadIdx.x] = 0;
}

__global__ __launch_bounds__(256) void compact_k(const float* __restrict__ scores,
                                                 const u32* __restrict__ kth,
                                                 u32* __restrict__ skeys, u32* __restrict__ sids,
                                                 u32* __restrict__ cnt) {
  const int b = blockIdx.y;
  const int g = blockIdx.x * 256 + threadIdx.x;
  if (g >= NANCH) return;
  u32 k = __float_as_uint(scores[(size_t)b * NANCH + g]);
  if (k >= kth[b]) {
    u32 slot = atomicAdd(&cnt[b], 1u);
    if (slot < SCAP) { skeys[(size_t)b * SCAP + slot] = k; sids[(size_t)b * SCAP + slot] = (u32)g; }
  }
}

__device__ inline bool prec_(u32 ka, u32 ia, u32 kb, u32 ib) {
  return (ka > kb) || (ka == kb && ia < ib);
}

__global__ __launch_bounds__(1024) void sort8k_k(const u32* __restrict__ skeys,
                                                 const u32* __restrict__ sids,
                                                 const u32* __restrict__ cnt,
                                                 u32* __restrict__ top_ids) {
  __shared__ u32 sk[SCAP];
  __shared__ u32 si[SCAP];
  const int b = blockIdx.x, tid = threadIdx.x;
  u32 cb = cnt[b]; if (cb > SCAP) cb = SCAP;
  for (int e = tid; e < SCAP; e += 1024) {
    u32 k = 0u; u32 id = 0xFFFFFFFFu;
    if (e < (int)cb) { k = skeys[(size_t)b * SCAP + e]; id = sids[(size_t)b * SCAP + e]; }
    sk[e] = k; si[e] = id;
  }
  __syncthreads();
  for (int k = 2; k <= SCAP; k <<= 1) {
    for (int j = k >> 1; j > 0; j >>= 1) {
      for (int t = tid; t < SCAP / 2; t += 1024) {
        int i = ((t & ~(j - 1)) << 1) | (t & (j - 1));
        int p2 = i | j;
        bool gf = ((i & k) == 0);   // final list descending
        u32 k1 = sk[i], k2 = sk[p2];
        u32 i1 = si[i], i2 = si[p2];
        bool sw = gf ? prec_(k2, i2, k1, i1) : prec_(k1, i1, k2, i2);
        if (sw) { sk[i] = k2; si[i] = i2; sk[p2] = k1; si[p2] = i1; }
      }
      __syncthreads();
    }
  }
  for (int e = tid; e < CAP; e += 1024)
    top_ids[(size_t)b * CAP + e] = si[e];
}

__global__ __launch_bounds__(256) void gather_k(const u32* __restrict__ top_ids,
                                                const float* __restrict__ prop,
                                                float* __restrict__ tb) {
  int t = blockIdx.x * 256 + threadIdx.x;
  if (t >= B_ * TOPN) return;
  int b = t / TOPN, r = t - b * TOPN;
  u32 g = top_ids[(size_t)b * CAP + r];
  size_t src = ((size_t)b * NANCH + g) * 4;
  size_t dst = ((size_t)b * CAP + r) * 4;
  tb[dst + 0] = prop[src + 0]; tb[dst + 1] = prop[src + 1];
  tb[dst + 2] = prop[src + 2]; tb[dst + 3] = prop[src + 3];
}

// ---------------- suppression bit-matrix (f32 IoU, same expression order) ----------------
// bit jj of supp[b][i][wj] set iff iou(i kept, j=wj*64+jj) > 0.7, iou = inter/(ar_i + ar_j - inter)
__global__ __launch_bounds__(256) void supp_k(const float* __restrict__ tb,
                                              u64* __restrict__ supp) {
  __shared__ float bx[64][5];
  const int b = blockIdx.z, wj = blockIdx.y;
  const int j0 = wj * 64;
  const int tid = threadIdx.x;
  if (tid < 64) {
    int j = j0 + tid;
    float x1 = 0.f, y1 = 0.f, x2 = -1.f, y2 = -1.f;
    if (j < TOPN) {
      size_t o = ((size_t)b * CAP + j) * 4;
      x1 = tb[o]; y1 = tb[o + 1]; x2 = tb[o + 2]; y2 = tb[o + 3];
    }
    bx[tid][0] = x1; bx[tid][1] = y1; bx[tid][2] = x2; bx[tid][3] = y2;
    bx[tid][4] = (x2 - x1 + 1.f) * (y2 - y1 + 1.f);
  }
  __syncthreads();
  int i = blockIdx.x * 256 + tid;
  if (i >= TOPN) return;
  size_t o = ((size_t)b * CAP + i) * 4;
  float x1 = tb[o], y1 = tb[o + 1], x2 = tb[o + 2], y2 = tb[o + 3];
  float ar = (x2 - x1 + 1.f) * (y2 - y1 + 1.f);
  u64 bits = 0;
  int jmax = TOPN - j0; if (jmax > 64) jmax = 64;
  for (int jj = 0; jj < jmax; ++jj) {
    float xx1 = fmaxf(x1, bx[jj][0]), yy1 = fmaxf(y1, bx[jj][1]);
    float xx2 = fminf(x2, bx[jj][2]), yy2 = fminf(y2, bx[jj][3]);
    float iw = fmaxf(xx2 - xx1 + 1.f, 0.f), ih = fmaxf(yy2 - yy1 + 1.f, 0.f);
    float inter = iw * ih;
    float iou = inter / (ar + bx[jj][4] - inter);
    if (iou > 0.7f) bits |= (1ull << jj);
  }
  supp[((size_t)b * TOPN + i) * WORDS + wj] = bits;
}

// sequential greedy NMS: 1 wave per batch, validity bitmask in registers (2 words/lane)
__global__ __launch_bounds__(64) void nms_k(const u64* __restrict__ supp,
                                            int* __restrict__ keep) {
  const int b = blockIdx.x;
  const int lane = threadIdx.x;
  const int w0i = 2 * lane, w1i = 2 * lane + 1;
  u64 v0 = (w0i < 93) ? ~0ull : (w0i == 93 ? ((1ull << 48) - 1) : 0ull);
  u64 v1 = (w1i < 93) ? ~0ull : (w1i == 93 ? ((1ull << 48) - 1) : 0ull);
  for (int it = 0; it < POST; ++it) {
    int cand = 0x7FFFFFFF;
    if (v0)      cand = w0i * 64 + (int)__builtin_ctzll(v0);
    else if (v1) cand = w1i * 64 + (int)__builtin_ctzll(v1);
#pragma unroll
    for (int off = 32; off > 0; off >>= 1) {
      int oc = __shfl_xor(cand, off);
      cand = oc < cand ? oc : cand;
    }
    if (cand == 0x7FFFFFFF) {
      if (lane == 0) keep[b * POST + it] = -1;
    } else {
      if (lane == 0) keep[b * POST + it] = cand;
      const u64* row = supp + ((size_t)b * TOPN + cand) * WORDS;
      if (w0i < WORDS) v0 &= ~row[w0i];
      if (w1i < WORDS) v1 &= ~row[w1i];
    }
  }
}

__global__ __launch_bounds__(256) void write_k(const int* __restrict__ keep,
                                               const float* __restrict__ tb,
                                               float* __restrict__ out) {
  int t = blockIdx.x * 256 + threadIdx.x;
  if (t >= B_ * POST) return;
  int b = t / POST;
  int r = keep[t];
  float* o = out + (size_t)t * 5;
  o[0] = (float)b;
  if (r >= 0) {
    size_t s = ((size_t)b * CAP + r) * 4;
    o[1] = tb[s]; o[2] = tb[s + 1];
    o[3] = tb[s + 2]; o[4] = tb[s + 3];
  } else {
    o[1] = 0.f; o[2] = 0.f; o[3] = 0.f; o[4] = 0.f;
  }
}

extern "C" void kernel_launch(void* const* d_in, const int* in_sizes, int n_in,
                              void* d_out, int out_size, void* d_ws, size_t ws_size,
                              hipStream_t stream) {
  const float* base_feat = (const float*)d_in[0];
  const float* im_info   = (const float*)d_in[1];
  const float* conv_w = (const float*)d_in[4];
  const float* conv_b = (const float*)d_in[5];
  const float* cls_w  = (const float*)d_in[6];
  const float* cls_b  = (const float*)d_in[7];
  const float* bbox_w = (const float*)d_in[8];
  const float* bbox_b = (const float*)d_in[9];

  char* ws = (char*)d_ws;
  float* rpn    = (float*)(ws + OFF_RPN);     // all 4 batches (50.3 MB)
  float* scores = (float*)(ws + OFF_SCORES);
  float* prop   = (float*)(ws + OFF_PROP);
  u32* skeys = (u32*)(ws + OFF_SKEYS);
  u32* sids  = (u32*)(ws + OFF_SIDS);
  u32* kth   = (u32*)(ws + OFF_KTH);
  u32* cnt   = (u32*)(ws + OFF_CNT);
  u32* tids  = (u32*)(ws + OFF_TID);
  float* topbox = (float*)(ws + OFF_TB);
  u64* supp  = (u64*)(ws + OFF_SUPP);
  int* keep  = (int*)(ws + OFF_KEEP);

  conv3_k<<<dim3(48, 8, B_), 256, 0, stream>>>(base_feat, conv_w, conv_b, rpn);
  head_k<<<dim3(24, B_), 256, 0, stream>>>(rpn, cls_w, cls_b, bbox_w, bbox_b, im_info, scores, prop);
  select_k<<<B_, 1024, 0, stream>>>(scores, kth);
  init_k<<<1, 64, 0, stream>>>(cnt);
  compact_k<<<dim3(216, B_), 256, 0, stream>>>(scores, kth, skeys, sids, cnt);
  sort8k_k<<<B_, 1024, 0, stream>>>(skeys, sids, cnt, tids);
  gather_k<<<94, 256, 0, stream>>>(tids, prop, topbox);
  supp_k<<<dim3(24, WORDS, B_), 256, 0, stream>>>(topbox, supp);
  nms_k<<<B_, 64, 0, stream>>>(supp, keep);
  write_k<<<5, 256, 0, stream>>>(keep, topbox, (float*)d_out);
}

// Round 7
// 4688.092 us; speedup vs baseline: 2.3790x; 1.1191x over previous
//
#include <hip/hip_runtime.h>
#include <math.h>

typedef unsigned long long u64;
typedef unsigned int u32;

#define B_     4
#define CIN    1024
#define COUT   512
#define H_     64
#define W_     96
#define HW     6144
#define NANCH  55296
#define TOPN   6000
#define POST   300
#define CAP    6144
#define WORDS  94
#define SCAP   8192

// workspace offsets (bytes, 256-aligned); total ~73.6 MB
#define OFF_RPN    0ull
#define OFF_SCORES 50331648ull
#define OFF_PROP   51216384ull
#define OFF_SKEYS  54755328ull
#define OFF_SIDS   54886400ull
#define OFF_KTH    55017472ull
#define OFF_CNT    55017728ull
#define OFF_TID    55017984ull
#define OFF_TB     55116288ull
#define OFF_SUPP   55509504ull
#define OFF_KEEP   73557504ull

__constant__ float BAf[9][4] = {
  {-84.f,-40.f,99.f,55.f},
  {-176.f,-88.f,191.f,103.f},
  {-360.f,-184.f,375.f,199.f},
  {-56.f,-56.f,71.f,71.f},
  {-120.f,-120.f,135.f,135.f},
  {-248.f,-248.f,263.f,263.f},
  {-36.f,-80.f,51.f,95.f},
  {-80.f,-168.f,95.f,183.f},
  {-168.f,-344.f,183.f,359.f}
};

// ---------------- 3x3 conv + bias + relu, fp32, all batches ----------------
// NUMERICS FROZEN: per-output FMA chain order (c asc, kh asc, kw asc) bit-matches
// the golden reference (round-5 absmax 0.0). Restructure parallelism only.
// Block: 256 thr, tm=pixel col (32), tn=cout octet (8 x 8 couts = 64 couts/block).
// Grid (24, 8, 4): x = cog(8) + 8*w3(3); y = h-tile; z = batch.
__global__ __launch_bounds__(256) void conv3_k(const float* __restrict__ x,
                                               const float* __restrict__ w,
                                               const float* __restrict__ bias,
                                               float* __restrict__ y) {
  __shared__ float patch[8][10][34];
  __shared__ float wl2[8][9][64];     // [ci][k][co] -> 8 contiguous weights per thread
  const int tid = threadIdx.x;
  const int cog = blockIdx.x & 7, w3 = blockIdx.x >> 3;
  const int h0 = blockIdx.y * 8;
  const int b = blockIdx.z;
  const int co0 = cog * 64, w0 = w3 * 32;
  const int tm = tid & 31, tn = tid >> 5;

  float acc[8][8];   // [pixel i][cout cc]
#pragma unroll
  for (int i = 0; i < 8; ++i)
#pragma unroll
    for (int cc = 0; cc < 8; ++cc)
      acc[i][cc] = 0.f;

  for (int c0 = 0; c0 < CIN; c0 += 8) {
    __syncthreads();
    for (int e = tid; e < 2720; e += 256) {
      int ci = e / 340, rem = e - ci * 340;
      int r = rem / 34, c = rem - r * 34;
      int hh = h0 - 1 + r, ww = w0 - 1 + c;
      float v = 0.f;
      if ((unsigned)hh < 64u && (unsigned)ww < 96u)
        v = x[(((size_t)b * CIN + c0 + ci) * H_ + hh) * W_ + ww];
      patch[ci][r][c] = v;
    }
    for (int e = tid; e < 4608; e += 256) {   // 8ci * 9k * 64co
      int g = e / 576, rem = e - g * 576;     // g = ci
      int co = rem / 9, k = rem - co * 9;     // k fastest in source -> short coalesced runs
      wl2[g][k][co] = w[(((size_t)(co0 + co)) * CIN + c0 + g) * 9 + k];
    }
    __syncthreads();
    for (int ci = 0; ci < 8; ++ci) {
      float col[3][10];
#pragma unroll
      for (int kw = 0; kw < 3; ++kw)
#pragma unroll
        for (int r = 0; r < 10; ++r)
          col[kw][r] = patch[ci][r][tm + kw];
#pragma unroll
      for (int kh = 0; kh < 3; ++kh) {
#pragma unroll
        for (int kw = 0; kw < 3; ++kw) {
          float wv[8];
#pragma unroll
          for (int cc = 0; cc < 8; ++cc) wv[cc] = wl2[ci][kh * 3 + kw][tn * 8 + cc];
#pragma unroll
          for (int cc = 0; cc < 8; ++cc)
#pragma unroll
            for (int i = 0; i < 8; ++i)
              acc[i][cc] = fmaf(col[kw][i + kh], wv[cc], acc[i][cc]);
        }
      }
    }
  }

#pragma unroll
  for (int cc = 0; cc < 8; ++cc) {
    float bv = bias[co0 + tn * 8 + cc];
#pragma unroll
    for (int i = 0; i < 8; ++i) {
      float v = acc[i][cc] + bv;
      v = v > 0.f ? v : 0.f;
      y[(((size_t)b * COUT + co0 + tn * 8 + cc) * H_ + (h0 + i)) * W_ + (w0 + tm)] = v;
    }
  }
}

// ------------- 1x1 heads + softmax + decode + clip (fp32), all batches -------------
__global__ __launch_bounds__(256) void head_k(const float* __restrict__ rpn,
    const float* __restrict__ wc, const float* __restrict__ bc,
    const float* __restrict__ wb, const float* __restrict__ bb,
    const float* __restrict__ iminfo,
    float* __restrict__ scores, float* __restrict__ prop) {
  __shared__ float wl[54][64];
  const int tid = threadIdx.x;
  const int s = blockIdx.x * 256 + tid;   // < 6144, uniform
  const int b = blockIdx.y;

  float acc[54];
  for (int o = 0; o < 54; ++o) acc[o] = 0.f;

  for (int c0 = 0; c0 < COUT; c0 += 64) {
    __syncthreads();
    for (int e = tid; e < 54 * 64; e += 256) {
      int o = e >> 6, c = e & 63;
      wl[o][c] = (o < 18 ? wc[o * COUT + c0 + c] : wb[(o - 18) * COUT + c0 + c]);
    }
    __syncthreads();
    for (int c = 0; c < 64; ++c) {
      float xv = rpn[((size_t)b * COUT + c0 + c) * HW + s];
      for (int o = 0; o < 54; ++o) acc[o] = fmaf(wl[o][c], xv, acc[o]);
    }
  }

  const float imh = iminfo[b * 3 + 0];
  const float imw = iminfo[b * 3 + 1];
  const int hh = s / W_, ww = s - hh * W_;

#pragma unroll
  for (int a = 0; a < 9; ++a) {
    float z0 = acc[a] + bc[a];
    float z1 = acc[9 + a] + bc[9 + a];
    float m = fmaxf(z0, z1);
    float e0 = expf(z0 - m), e1 = expf(z1 - m);
    float sc = e1 / (e0 + e1);

    float d0 = acc[18 + 4 * a + 0] + bb[4 * a + 0];
    float d1 = acc[18 + 4 * a + 1] + bb[4 * a + 1];
    float d2 = acc[18 + 4 * a + 2] + bb[4 * a + 2];
    float d3 = acc[18 + 4 * a + 3] + bb[4 * a + 3];

    float ax1 = BAf[a][0] + 16.f * ww, ay1 = BAf[a][1] + 16.f * hh;
    float ax2 = BAf[a][2] + 16.f * ww, ay2 = BAf[a][3] + 16.f * hh;
    float wa = ax2 - ax1 + 1.f, ha = ay2 - ay1 + 1.f;
    float cxa = ax1 + 0.5f * wa, cya = ay1 + 0.5f * ha;
    float cx = d0 * wa + cxa, cy = d1 * ha + cya;
    float pw = expf(d2) * wa, ph = expf(d3) * ha;
    float px1 = cx - 0.5f * pw, py1 = cy - 0.5f * ph;
    float px2 = cx + 0.5f * pw, py2 = cy + 0.5f * ph;
    px1 = fminf(fmaxf(px1, 0.f), imw - 1.f);
    px2 = fminf(fmaxf(px2, 0.f), imw - 1.f);
    py1 = fminf(fmaxf(py1, 0.f), imh - 1.f);
    py2 = fminf(fmaxf(py2, 0.f), imh - 1.f);

    size_t ai = (size_t)b * NANCH + (size_t)s * 9 + a;
    scores[ai] = sc;
    prop[ai * 4 + 0] = px1; prop[ai * 4 + 1] = py1;
    prop[ai * 4 + 2] = px2; prop[ai * 4 + 3] = py2;
  }
}

// ---------------- exact top-6000 selection on f32-bit keys ----------------
__global__ __launch_bounds__(1024) void select_k(const float* __restrict__ scores,
                                                 u32* __restrict__ kth) {
  __shared__ u32 hist[256];
  __shared__ u32 sh_pref;
  __shared__ u32 sh_r;
  const int b = blockIdx.x, tid = threadIdx.x;
  const float* sb = scores + (size_t)b * NANCH;
  if (tid == 0) { sh_pref = 0u; sh_r = TOPN; }
  __syncthreads();
  for (int d = 3; d >= 0; --d) {
    if (tid < 256) hist[tid] = 0;
    __syncthreads();
    u32 pref = sh_pref;
    u32 mask = (d == 3) ? 0u : (0xFFFFFFFFu << ((d + 1) * 8));
    for (int g = tid; g < NANCH; g += 1024) {
      u32 k = __float_as_uint(sb[g]);
      if ((k & mask) == pref)
        atomicAdd(&hist[(k >> (d * 8)) & 0xFFu], 1u);
    }
    __syncthreads();
    if (tid == 0) {
      u32 r = sh_r, cum = 0;
      for (int bin = 255; bin >= 0; --bin) {
        u32 c = hist[bin];
        if (cum + c >= r) { sh_r = r - cum; sh_pref = pref | ((u32)bin << (d * 8)); break; }
        cum += c;
      }
    }
    __syncthreads();
  }
  if (tid == 0) kth[b] = sh_pref;
}

__global__ void init_k(u32* cnt) {
  if (threadIdx.x < B_) cnt[threadIdx.x] = 0;
}

__global__ __launch_bounds__(256) void compact_k(const float* __restrict__ scores,
                                                 const u32* __restrict__ kth,
                                                 u32* __restrict__ skeys, u32* __restrict__ sids,
                                                 u32* __restrict__ cnt) {
  const int b = blockIdx.y;
  const int g = blockIdx.x * 256 + threadIdx.x;
  if (g >= NANCH) return;
  u32 k = __float_as_uint(scores[(size_t)b * NANCH + g]);
  if (k >= kth[b]) {
    u32 slot = atomicAdd(&cnt[b], 1u);
    if (slot < SCAP) { skeys[(size_t)b * SCAP + slot] = k; sids[(size_t)b * SCAP + slot] = (u32)g; }
  }
}

__device__ inline bool prec_(u32 ka, u32 ia, u32 kb, u32 ib) {
  return (ka > kb) || (ka == kb && ia < ib);
}

__global__ __launch_bounds__(1024) void sort8k_k(const u32* __restrict__ skeys,
                                                 const u32* __restrict__ sids,
                                                 const u32* __restrict__ cnt,
                                                 u32* __restrict__ top_ids) {
  __shared__ u32 sk[SCAP];
  __shared__ u32 si[SCAP];
  const int b = blockIdx.x, tid = threadIdx.x;
  u32 cb = cnt[b]; if (cb > SCAP) cb = SCAP;
  for (int e = tid; e < SCAP; e += 1024) {
    u32 k = 0u; u32 id = 0xFFFFFFFFu;
    if (e < (int)cb) { k = skeys[(size_t)b * SCAP + e]; id = sids[(size_t)b * SCAP + e]; }
    sk[e] = k; si[e] = id;
  }
  __syncthreads();
  for (int k = 2; k <= SCAP; k <<= 1) {
    for (int j = k >> 1; j > 0; j >>= 1) {
      for (int t = tid; t < SCAP / 2; t += 1024) {
        int i = ((t & ~(j - 1)) << 1) | (t & (j - 1));
        int p2 = i | j;
        bool gf = ((i & k) == 0);   // final list descending
        u32 k1 = sk[i], k2 = sk[p2];
        u32 i1 = si[i], i2 = si[p2];
        bool sw = gf ? prec_(k2, i2, k1, i1) : prec_(k1, i1, k2, i2);
        if (sw) { sk[i] = k2; si[i] = i2; sk[p2] = k1; si[p2] = i1; }
      }
      __syncthreads();
    }
  }
  for (int e = tid; e < CAP; e += 1024)
    top_ids[(size_t)b * CAP + e] = si[e];
}

__global__ __launch_bounds__(256) void gather_k(const u32* __restrict__ top_ids,
                                                const float* __restrict__ prop,
                                                float* __restrict__ tb) {
  int t = blockIdx.x * 256 + threadIdx.x;
  if (t >= B_ * TOPN) return;
  int b = t / TOPN, r = t - b * TOPN;
  u32 g = top_ids[(size_t)b * CAP + r];
  size_t src = ((size_t)b * NANCH + g) * 4;
  size_t dst = ((size_t)b * CAP + r) * 4;
  tb[dst + 0] = prop[src + 0]; tb[dst + 1] = prop[src + 1];
  tb[dst + 2] = prop[src + 2]; tb[dst + 3] = prop[src + 3];
}

// ---------------- suppression bit-matrix (f32 IoU, same expression order) ----------------
__global__ __launch_bounds__(256) void supp_k(const float* __restrict__ tb,
                                              u64* __restrict__ supp) {
  __shared__ float bx[64][5];
  const int b = blockIdx.z, wj = blockIdx.y;
  const int j0 = wj * 64;
  const int tid = threadIdx.x;
  if (tid < 64) {
    int j = j0 + tid;
    float x1 = 0.f, y1 = 0.f, x2 = -1.f, y2 = -1.f;
    if (j < TOPN) {
      size_t o = ((size_t)b * CAP + j) * 4;
      x1 = tb[o]; y1 = tb[o + 1]; x2 = tb[o + 2]; y2 = tb[o + 3];
    }
    bx[tid][0] = x1; bx[tid][1] = y1; bx[tid][2] = x2; bx[tid][3] = y2;
    bx[tid][4] = (x2 - x1 + 1.f) * (y2 - y1 + 1.f);
  }
  __syncthreads();
  int i = blockIdx.x * 256 + tid;
  if (i >= TOPN) return;
  size_t o = ((size_t)b * CAP + i) * 4;
  float x1 = tb[o], y1 = tb[o + 1], x2 = tb[o + 2], y2 = tb[o + 3];
  float ar = (x2 - x1 + 1.f) * (y2 - y1 + 1.f);
  u64 bits = 0;
  int jmax = TOPN - j0; if (jmax > 64) jmax = 64;
  for (int jj = 0; jj < jmax; ++jj) {
    float xx1 = fmaxf(x1, bx[jj][0]), yy1 = fmaxf(y1, bx[jj][1]);
    float xx2 = fminf(x2, bx[jj][2]), yy2 = fminf(y2, bx[jj][3]);
    float iw = fmaxf(xx2 - xx1 + 1.f, 0.f), ih = fmaxf(yy2 - yy1 + 1.f, 0.f);
    float inter = iw * ih;
    float iou = inter / (ar + bx[jj][4] - inter);
    if (iou > 0.7f) bits |= (1ull << jj);
  }
  supp[((size_t)b * TOPN + i) * WORDS + wj] = bits;
}

// sequential greedy NMS: 1 wave per batch, validity bitmask in registers
__global__ __launch_bounds__(64) void nms_k(const u64* __restrict__ supp,
                                            int* __restrict__ keep) {
  const int b = blockIdx.x;
  const int lane = threadIdx.x;
  const int w0i = 2 * lane, w1i = 2 * lane + 1;
  u64 v0 = (w0i < 93) ? ~0ull : (w0i == 93 ? ((1ull << 48) - 1) : 0ull);
  u64 v1 = (w1i < 93) ? ~0ull : (w1i == 93 ? ((1ull << 48) - 1) : 0ull);
  for (int it = 0; it < POST; ++it) {
    int cand = 0x7FFFFFFF;
    if (v0)      cand = w0i * 64 + (int)__builtin_ctzll(v0);
    else if (v1) cand = w1i * 64 + (int)__builtin_ctzll(v1);
#pragma unroll
    for (int off = 32; off > 0; off >>= 1) {
      int oc = __shfl_xor(cand, off);
      cand = oc < cand ? oc : cand;
    }
    if (cand == 0x7FFFFFFF) {
      if (lane == 0) keep[b * POST + it] = -1;
    } else {
      if (lane == 0) keep[b * POST + it] = cand;
      const u64* row = supp + ((size_t)b * TOPN + cand) * WORDS;
      if (w0i < WORDS) v0 &= ~row[w0i];
      if (w1i < WORDS) v1 &= ~row[w1i];
    }
  }
}

__global__ __launch_bounds__(256) void write_k(const int* __restrict__ keep,
                                               const float* __restrict__ tb,
                                               float* __restrict__ out) {
  int t = blockIdx.x * 256 + threadIdx.x;
  if (t >= B_ * POST) return;
  int b = t / POST;
  int r = keep[t];
  float* o = out + (size_t)t * 5;
  o[0] = (float)b;
  if (r >= 0) {
    size_t s = ((size_t)b * CAP + r) * 4;
    o[1] = tb[s]; o[2] = tb[s + 1];
    o[3] = tb[s + 2]; o[4] = tb[s + 3];
  } else {
    o[1] = 0.f; o[2] = 0.f; o[3] = 0.f; o[4] = 0.f;
  }
}

extern "C" void kernel_launch(void* const* d_in, const int* in_sizes, int n_in,
                              void* d_out, int out_size, void* d_ws, size_t ws_size,
                              hipStream_t stream) {
  const float* base_feat = (const float*)d_in[0];
  const float* im_info   = (const float*)d_in[1];
  const float* conv_w = (const float*)d_in[4];
  const float* conv_b = (const float*)d_in[5];
  const float* cls_w  = (const float*)d_in[6];
  const float* cls_b  = (const float*)d_in[7];
  const float* bbox_w = (const float*)d_in[8];
  const float* bbox_b = (const float*)d_in[9];

  char* ws = (char*)d_ws;
  float* rpn    = (float*)(ws + OFF_RPN);
  float* scores = (float*)(ws + OFF_SCORES);
  float* prop   = (float*)(ws + OFF_PROP);
  u32* skeys = (u32*)(ws + OFF_SKEYS);
  u32* sids  = (u32*)(ws + OFF_SIDS);
  u32* kth   = (u32*)(ws + OFF_KTH);
  u32* cnt   = (u32*)(ws + OFF_CNT);
  u32* tids  = (u32*)(ws + OFF_TID);
  float* topbox = (float*)(ws + OFF_TB);
  u64* supp  = (u64*)(ws + OFF_SUPP);
  int* keep  = (int*)(ws + OFF_KEEP);

  conv3_k<<<dim3(24, 8, B_), 256, 0, stream>>>(base_feat, conv_w, conv_b, rpn);
  head_k<<<dim3(24, B_), 256, 0, stream>>>(rpn, cls_w, cls_b, bbox_w, bbox_b, im_info, scores, prop);
  select_k<<<B_, 1024, 0, stream>>>(scores, kth);
  init_k<<<1, 64, 0, stream>>>(cnt);
  compact_k<<<dim3(216, B_), 256, 0, stream>>>(scores, kth, skeys, sids, cnt);
  sort8k_k<<<B_, 1024, 0, stream>>>(skeys, sids, cnt, tids);
  gather_k<<<94, 256, 0, stream>>>(tids, prop, topbox);
  supp_k<<<dim3(24, WORDS, B_), 256, 0, stream>>>(topbox, supp);
  nms_k<<<B_, 64, 0, stream>>>(supp, keep);
  write_k<<<5, 256, 0, stream>>>(keep, topbox, (float*)d_out);
}